// Round 1
// baseline (558.183 us; speedup 1.0000x reference)
//
#include <hip/hip_runtime.h>
#include <hip/hip_bf16.h>

// ---------------------------------------------------------------------------
// swin_transformer_angular_tan: qkv GEMM -> windowed attention (+trig rel-pos
// bias) -> proj GEMM.  B=1024 windows x 64 tokens, DIM=512, 16 heads x 32.
// Pipeline: cvt(x,w) -> bias table -> qkv bf16 GEMM -> attn (MFMA, register
// softmax) -> proj GEMM (fp32 out).
// ---------------------------------------------------------------------------

typedef __bf16 bf16_t;
typedef bf16_t bf16x8 __attribute__((ext_vector_type(8)));
typedef float  f32x4  __attribute__((ext_vector_type(4)));

#define NWIN   1024
#define NTOK   64
#define DIM    512
#define NHEADS 16
#define HD     32
#define MTOT   (NWIN*NTOK)      // 65536
#define QKVN   (3*DIM)          // 1536
#define SCALE  0.17677669529663687f   // 1/sqrt(32)

// ---------------- async global->LDS (16B per lane, wave-uniform LDS base) ---
__device__ __forceinline__ void async_copy16(const void* g, void* lds_generic) {
    __builtin_amdgcn_global_load_lds(
        (__attribute__((address_space(1))) unsigned int*)(unsigned long long)g,
        (__attribute__((address_space(3))) unsigned int*)(unsigned int)(unsigned long long)lds_generic,
        16, 0, 0);
}

// ---------------- fp32 -> bf16 convert (8 elems/thread) ---------------------
__global__ void cvt_f32_bf16(const float* __restrict__ in, bf16_t* __restrict__ out, int n8) {
    int i = blockIdx.x * blockDim.x + threadIdx.x;
    if (i >= n8) return;
    const float4* p = (const float4*)in;
    float4 a = p[2*i], b = p[2*i+1];
    bf16x8 o;
    o[0]=(bf16_t)a.x; o[1]=(bf16_t)a.y; o[2]=(bf16_t)a.z; o[3]=(bf16_t)a.w;
    o[4]=(bf16_t)b.x; o[5]=(bf16_t)b.y; o[6]=(bf16_t)b.z; o[7]=(bf16_t)b.w;
    ((bf16x8*)out)[i] = o;
}

// ---------------- bias table: bias[h][i][j], 16 x 64 x 64 -------------------
__global__ void bias_kernel(const float* __restrict__ ap, const float* __restrict__ bp,
                            const float* __restrict__ ar, const float* __restrict__ br,
                            const float* __restrict__ theta_max, float* __restrict__ bias) {
    int idx = blockIdx.x * 256 + threadIdx.x;   // 0..65535
    int h  = idx >> 12;
    int ij = idx & 4095;
    int i = ij >> 6, j = ij & 63;
    int ri = i >> 3, ci = i & 7, rj = j >> 3, cj = j & 7;
    int rad = ri - rj, az = ci - cj;              // -7..7
    int idx_r  = rad < 0 ? rad + 15 : rad;        // python % 15
    int idx_az = az  < 0 ? az  + 15 : az;
    float azang = (float)az * 0.19634954084936207f;       // 2*pi/32
    float rang  = (float)rad * (theta_max[0] * (1.0f/32.0f));
    float v = ap[idx_az*NHEADS + h] * cosf(azang) + bp[idx_az*NHEADS + h] * sinf(azang)
            + ar[idx_r *NHEADS + h] * cosf(rang)  + br[idx_r *NHEADS + h] * sinf(rang);
    bias[idx] = v;
}

// ---------------- BT-GEMM: C[M,N] = A[M,K] * Bt[N,K]^T + bias[N] ------------
// 128x128 tile, BK=64, 4 waves each 64x64 (4x4 MFMA 16x16x32).
// LDS tiles XOR-swizzled: row r, 16B-chunk cb stored at position cb^(r&7).
template<int OUT_BF16>
__global__ __launch_bounds__(256, 2)
void gemm_bt(const bf16_t* __restrict__ A, const bf16_t* __restrict__ Bt,
             const float* __restrict__ bias, void* __restrict__ C,
             int M, int N, int K, int ntiles) {
    __shared__ bf16_t sA[128*64];
    __shared__ bf16_t sB[128*64];

    int bid = blockIdx.x;
    int bm = bid / ntiles, bn = bid % ntiles;
    int tid = threadIdx.x;
    int w = tid >> 6, lane = tid & 63;
    int quad = lane >> 4, l16 = lane & 15;
    int wm = w >> 1, wn = w & 1;               // 2x2 wave grid

    f32x4 acc[4][4] = {};

    const bf16_t* Abase = A  + (size_t)(bm*128) * K;
    const bf16_t* Bbase = Bt + (size_t)(bn*128) * K;

    for (int k0 = 0; k0 < K; k0 += 64) {
        // ---- stage A (16KB) and B (16KB): 4 x 1KB insts per wave each ----
        for (int i = 0; i < 4; ++i) {
            int off = w*4096 + i*1024 + lane*16;  // byte offset in tile
            int r  = off >> 7;                    // row (128B rows)
            int pb = (off >> 4) & 7;              // physical 16B chunk
            int cb = pb ^ (r & 7);                // logical chunk (swizzle)
            async_copy16(Abase + (size_t)r*K + k0 + cb*8, (char*)sA + w*4096 + i*1024);
            async_copy16(Bbase + (size_t)r*K + k0 + cb*8, (char*)sB + w*4096 + i*1024);
        }
        __syncthreads();

        // ---- compute: 2 K-steps of 32, 4x4 tiles ----
        for (int kk = 0; kk < 64; kk += 32) {
            bf16x8 af[4], bf[4];
            for (int mi = 0; mi < 4; ++mi) {
                int r  = wm*64 + mi*16 + l16;
                int cb = (kk >> 3) + quad;
                int pb = cb ^ (r & 7);
                af[mi] = *(const bf16x8*)((const char*)sA + r*128 + pb*16);
            }
            for (int ni = 0; ni < 4; ++ni) {
                int r  = wn*64 + ni*16 + l16;
                int cb = (kk >> 3) + quad;
                int pb = cb ^ (r & 7);
                bf[ni] = *(const bf16x8*)((const char*)sB + r*128 + pb*16);
            }
            for (int mi = 0; mi < 4; ++mi)
                for (int ni = 0; ni < 4; ++ni)
                    acc[mi][ni] = __builtin_amdgcn_mfma_f32_16x16x32_bf16(
                        af[mi], bf[ni], acc[mi][ni], 0, 0, 0);
        }
        __syncthreads();
    }

    // ---- epilogue: +bias, store (C/D layout: row=quad*4+reg, col=l16) ----
    for (int ni = 0; ni < 4; ++ni) {
        int col = bn*128 + wn*64 + ni*16 + l16;
        float bv = bias[col];
        for (int mi = 0; mi < 4; ++mi) {
            int row0 = bm*128 + wm*64 + mi*16 + quad*4;
            f32x4 a = acc[mi][ni];
            for (int reg = 0; reg < 4; ++reg) {
                float v = a[reg] + bv;
                size_t o = (size_t)(row0 + reg) * N + col;
                if (OUT_BF16) ((bf16_t*)C)[o] = (bf16_t)v;
                else          ((float*)C)[o]  = v;
            }
        }
    }
}

// ---------------- attention: one block per (window, head) -------------------
// qkv layout: [m,1536] rows; q at col h*32, k at 512+h*32, v at 1024+h*32.
// 4 waves, wave w owns S rows 16w..16w+15 (all 64 cols) -> register softmax
// (quad shuffles) -> P to LDS (bf16, stride 72 to dodge conflicts) -> PV MFMA
// with vT staged in LDS -> out[m, h*32+d] bf16.
__global__ __launch_bounds__(256)
void attn_kernel(const bf16_t* __restrict__ qkv, const float* __restrict__ bias,
                 bf16_t* __restrict__ h2) {
    __shared__ bf16_t P[64*72];
    __shared__ bf16_t vT[32*64];

    int b = blockIdx.x >> 4, h = blockIdx.x & 15;
    int tid = threadIdx.x;
    int w = tid >> 6, lane = tid & 63, quad = lane >> 4, l16 = lane & 15;
    const bf16_t* base = qkv + (size_t)(b*64) * QKVN;

    // stage v transposed: vT[d][t]
    {
        int t = tid & 63, dg = tid >> 6;
        bf16x8 vv = *(const bf16x8*)(base + (size_t)t*QKVN + 1024 + h*32 + dg*8);
        for (int j = 0; j < 8; ++j) vT[(dg*8 + j)*64 + t] = vv[j];
    }

    int m0 = w * 16;
    // S = q k^T : A-frag = q rows, B-frag = k rows (row-load == k^T operand)
    bf16x8 aq = *(const bf16x8*)(base + (size_t)(m0 + l16)*QKVN + h*32 + quad*8);
    f32x4 zero = {0.f, 0.f, 0.f, 0.f};
    f32x4 accS[4];
    for (int jt = 0; jt < 4; ++jt) {
        bf16x8 bk = *(const bf16x8*)(base + (size_t)(jt*16 + l16)*QKVN + 512 + h*32 + quad*8);
        accS[jt] = __builtin_amdgcn_mfma_f32_16x16x32_bf16(aq, bk, zero, 0, 0, 0);
    }

    // logits + softmax, fully in registers (row r = m0 + quad*4 + reg;
    // the 64 cols of row r live in the 16 lanes of this quad x 4 jt)
    const float* bh = bias + h*4096;
    float p[4][4], inv[4];
    for (int reg = 0; reg < 4; ++reg) {
        int row = m0 + quad*4 + reg;
        for (int jt = 0; jt < 4; ++jt)
            p[jt][reg] = accS[jt][reg] * SCALE + bh[row*64 + jt*16 + l16];
        float m = fmaxf(fmaxf(p[0][reg], p[1][reg]), fmaxf(p[2][reg], p[3][reg]));
        for (int off = 1; off < 16; off <<= 1) m = fmaxf(m, __shfl_xor(m, off));
        float s = 0.f;
        for (int jt = 0; jt < 4; ++jt) { p[jt][reg] = __expf(p[jt][reg] - m); s += p[jt][reg]; }
        for (int off = 1; off < 16; off <<= 1) s += __shfl_xor(s, off);
        inv[reg] = 1.0f / s;
    }
    // write P (bf16) for the PV A-operand
    for (int reg = 0; reg < 4; ++reg) {
        int row = m0 + quad*4 + reg;
        for (int jt = 0; jt < 4; ++jt)
            P[row*72 + jt*16 + l16] = (bf16_t)p[jt][reg];
    }
    __syncthreads();

    // O = P v : K=64 (2 steps), N=32 (2 tiles)
    f32x4 accO[2] = {zero, zero};
    for (int kb = 0; kb < 64; kb += 32) {
        bf16x8 ap = *(const bf16x8*)(&P[(m0 + l16)*72 + kb + quad*8]);
        for (int nt = 0; nt < 2; ++nt) {
            bf16x8 bv = *(const bf16x8*)(&vT[(nt*16 + l16)*64 + kb + quad*8]);
            accO[nt] = __builtin_amdgcn_mfma_f32_16x16x32_bf16(ap, bv, accO[nt], 0, 0, 0);
        }
    }
    // store: out row = token, col = h*32 + nt*16 + l16  (rescale by 1/rowsum)
    for (int nt = 0; nt < 2; ++nt) {
        for (int reg = 0; reg < 4; ++reg) {
            int row = b*64 + m0 + quad*4 + reg;
            int col = h*32 + nt*16 + l16;
            h2[(size_t)row*DIM + col] = (bf16_t)(accO[nt][reg] * inv[reg]);
        }
    }
}

// ---------------------------------------------------------------------------
extern "C" void kernel_launch(void* const* d_in, const int* in_sizes, int n_in,
                              void* d_out, int out_size, void* d_ws, size_t ws_size,
                              hipStream_t stream) {
    const float* x      = (const float*)d_in[0];
    const float* theta  = (const float*)d_in[1];
    const float* qkv_w  = (const float*)d_in[2];
    const float* qkv_b  = (const float*)d_in[3];
    const float* proj_w = (const float*)d_in[4];
    const float* proj_b = (const float*)d_in[5];
    const float* a_p    = (const float*)d_in[6];
    const float* b_p    = (const float*)d_in[7];
    const float* a_r    = (const float*)d_in[8];
    const float* b_r    = (const float*)d_in[9];
    float* out = (float*)d_out;

    // workspace layout (all 256B aligned); total ~338 MB
    char* ws = (char*)d_ws;
    bf16_t* qkvbuf = (bf16_t*)ws;                                  // 65536*1536 bf16 = 192MB
    bf16_t* xb     = (bf16_t*)(ws + 201326592);                    // 65536*512  bf16 = 64MB
    bf16_t* h2     = (bf16_t*)(ws + 201326592 + 67108864);         // 65536*512  bf16 = 64MB
    bf16_t* wqkv   = (bf16_t*)(ws + 201326592 + 2*67108864);       // 1536*512 bf16
    bf16_t* wproj  = (bf16_t*)(ws + 201326592 + 2*67108864 + 1572864);
    float*  biasbf = (float*) (ws + 201326592 + 2*67108864 + 1572864 + 524288);

    // 1) converts
    cvt_f32_bf16<<<(MTOT*DIM/8)/256, 256, 0, stream>>>(x, xb, MTOT*DIM/8);          // 4194304
    cvt_f32_bf16<<<(QKVN*DIM/8)/256, 256, 0, stream>>>(qkv_w, wqkv, QKVN*DIM/8);    // 98304
    cvt_f32_bf16<<<(DIM*DIM/8)/256, 256, 0, stream>>>(proj_w, wproj, DIM*DIM/8);    // 32768

    // 2) bias table
    bias_kernel<<<256, 256, 0, stream>>>(a_p, b_p, a_r, b_r, theta, biasbf);

    // 3) qkv GEMM: M=65536 N=1536 K=512 (bf16 out)
    gemm_bt<1><<<(MTOT/128)*(QKVN/128), 256, 0, stream>>>(xb, wqkv, qkv_b, qkvbuf,
                                                          MTOT, QKVN, DIM, QKVN/128);
    // 4) attention
    attn_kernel<<<NWIN*NHEADS, 256, 0, stream>>>(qkvbuf, biasbf, h2);

    // 5) proj GEMM: M=65536 N=512 K=512 (fp32 out)
    gemm_bt<0><<<(MTOT/128)*(DIM/128), 256, 0, stream>>>(h2, wproj, proj_b, out,
                                                         MTOT, DIM, DIM, DIM/128);
}

// Round 2
// 534.686 us; speedup vs baseline: 1.0439x; 1.0439x over previous
//
#include <hip/hip_runtime.h>
#include <hip/hip_bf16.h>

// ---------------------------------------------------------------------------
// swin_transformer_angular_tan: qkv GEMM -> fused (windowed attention + proj).
// B=1024 windows x 64 tokens, DIM=512, 16 heads x 32.
// Pipeline: cvt(x,w) -> bias table -> qkv bf16 GEMM -> fused attn+proj (fp32
// out).  Fusion keeps attnout in LDS (bf16) and streams proj_w from L2,
// eliminating the h2 HBM round-trip and the standalone proj GEMM.
// ---------------------------------------------------------------------------

typedef __bf16 bf16_t;
typedef bf16_t bf16x8 __attribute__((ext_vector_type(8)));
typedef float  f32x4  __attribute__((ext_vector_type(4)));

#define NWIN   1024
#define NTOK   64
#define DIM    512
#define NHEADS 16
#define HD     32
#define MTOT   (NWIN*NTOK)      // 65536
#define QKVN   (3*DIM)          // 1536
#define SCALE  0.17677669529663687f   // 1/sqrt(32)

// ---------------- async global->LDS (16B per lane, wave-uniform LDS base) ---
__device__ __forceinline__ void async_copy16(const void* g, void* lds_generic) {
    __builtin_amdgcn_global_load_lds(
        (__attribute__((address_space(1))) unsigned int*)(unsigned long long)g,
        (__attribute__((address_space(3))) unsigned int*)(unsigned int)(unsigned long long)lds_generic,
        16, 0, 0);
}

// ---------------- fp32 -> bf16 convert (8 elems/thread) ---------------------
__global__ void cvt_f32_bf16(const float* __restrict__ in, bf16_t* __restrict__ out, int n8) {
    int i = blockIdx.x * blockDim.x + threadIdx.x;
    if (i >= n8) return;
    const float4* p = (const float4*)in;
    float4 a = p[2*i], b = p[2*i+1];
    bf16x8 o;
    o[0]=(bf16_t)a.x; o[1]=(bf16_t)a.y; o[2]=(bf16_t)a.z; o[3]=(bf16_t)a.w;
    o[4]=(bf16_t)b.x; o[5]=(bf16_t)b.y; o[6]=(bf16_t)b.z; o[7]=(bf16_t)b.w;
    ((bf16x8*)out)[i] = o;
}

// ---------------- bias table: bias[h][i][j], 16 x 64 x 64 -------------------
__global__ void bias_kernel(const float* __restrict__ ap, const float* __restrict__ bp,
                            const float* __restrict__ ar, const float* __restrict__ br,
                            const float* __restrict__ theta_max, float* __restrict__ bias) {
    int idx = blockIdx.x * 256 + threadIdx.x;   // 0..65535
    int h  = idx >> 12;
    int ij = idx & 4095;
    int i = ij >> 6, j = ij & 63;
    int ri = i >> 3, ci = i & 7, rj = j >> 3, cj = j & 7;
    int rad = ri - rj, az = ci - cj;              // -7..7
    int idx_r  = rad < 0 ? rad + 15 : rad;        // python % 15
    int idx_az = az  < 0 ? az  + 15 : az;
    float azang = (float)az * 0.19634954084936207f;       // 2*pi/32
    float rang  = (float)rad * (theta_max[0] * (1.0f/32.0f));
    float v = ap[idx_az*NHEADS + h] * cosf(azang) + bp[idx_az*NHEADS + h] * sinf(azang)
            + ar[idx_r *NHEADS + h] * cosf(rang)  + br[idx_r *NHEADS + h] * sinf(rang);
    bias[idx] = v;
}

// ---------------- BT-GEMM: C[M,N] = A[M,K] * Bt[N,K]^T + bias[N] ------------
// 128x128 tile, BK=64, 4 waves each 64x64 (4x4 MFMA 16x16x32).
// LDS tiles XOR-swizzled: row r, 16B-chunk cb stored at position cb^(r&7).
template<int OUT_BF16>
__global__ __launch_bounds__(256, 2)
void gemm_bt(const bf16_t* __restrict__ A, const bf16_t* __restrict__ Bt,
             const float* __restrict__ bias, void* __restrict__ C,
             int M, int N, int K, int ntiles) {
    __shared__ bf16_t sA[128*64];
    __shared__ bf16_t sB[128*64];

    int bid = blockIdx.x;
    int bm = bid / ntiles, bn = bid % ntiles;
    int tid = threadIdx.x;
    int w = tid >> 6, lane = tid & 63;
    int quad = lane >> 4, l16 = lane & 15;
    int wm = w >> 1, wn = w & 1;               // 2x2 wave grid

    f32x4 acc[4][4] = {};

    const bf16_t* Abase = A  + (size_t)(bm*128) * K;
    const bf16_t* Bbase = Bt + (size_t)(bn*128) * K;

    for (int k0 = 0; k0 < K; k0 += 64) {
        // ---- stage A (16KB) and B (16KB): 4 x 1KB insts per wave each ----
        for (int i = 0; i < 4; ++i) {
            int off = w*4096 + i*1024 + lane*16;  // byte offset in tile
            int r  = off >> 7;                    // row (128B rows)
            int pb = (off >> 4) & 7;              // physical 16B chunk
            int cb = pb ^ (r & 7);                // logical chunk (swizzle)
            async_copy16(Abase + (size_t)r*K + k0 + cb*8, (char*)sA + w*4096 + i*1024);
            async_copy16(Bbase + (size_t)r*K + k0 + cb*8, (char*)sB + w*4096 + i*1024);
        }
        __syncthreads();

        // ---- compute: 2 K-steps of 32, 4x4 tiles ----
        for (int kk = 0; kk < 64; kk += 32) {
            bf16x8 af[4], bf[4];
            for (int mi = 0; mi < 4; ++mi) {
                int r  = wm*64 + mi*16 + l16;
                int cb = (kk >> 3) + quad;
                int pb = cb ^ (r & 7);
                af[mi] = *(const bf16x8*)((const char*)sA + r*128 + pb*16);
            }
            for (int ni = 0; ni < 4; ++ni) {
                int r  = wn*64 + ni*16 + l16;
                int cb = (kk >> 3) + quad;
                int pb = cb ^ (r & 7);
                bf[ni] = *(const bf16x8*)((const char*)sB + r*128 + pb*16);
            }
            for (int mi = 0; mi < 4; ++mi)
                for (int ni = 0; ni < 4; ++ni)
                    acc[mi][ni] = __builtin_amdgcn_mfma_f32_16x16x32_bf16(
                        af[mi], bf[ni], acc[mi][ni], 0, 0, 0);
        }
        __syncthreads();
    }

    // ---- epilogue: +bias, store (C/D layout: row=quad*4+reg, col=l16) ----
    for (int ni = 0; ni < 4; ++ni) {
        int col = bn*128 + wn*64 + ni*16 + l16;
        float bv = bias[col];
        for (int mi = 0; mi < 4; ++mi) {
            int row0 = bm*128 + wm*64 + mi*16 + quad*4;
            f32x4 a = acc[mi][ni];
            for (int reg = 0; reg < 4; ++reg) {
                float v = a[reg] + bv;
                size_t o = (size_t)(row0 + reg) * N + col;
                if (OUT_BF16) ((bf16_t*)C)[o] = (bf16_t)v;
                else          ((float*)C)[o]  = v;
            }
        }
    }
}

// ---------------- fused attention + proj: one block per window --------------
// Phase 1 (loop h=0..15): register-softmax attention per head (as before),
// attnout accumulated into LDS aout[64][520] bf16.
// Phase 2: out[64,512] = aout @ proj_w^T + proj_b, MFMA with proj_w B-frags
// streamed from global (L2-resident: every block reads the same 512KB).
// LDS strides: aout 520 (4-bank rot), P 72, vT 72 -- all 2-way max (free).
__global__ __launch_bounds__(256, 2)
void attn_proj_kernel(const bf16_t* __restrict__ qkv, const float* __restrict__ bias,
                      const bf16_t* __restrict__ projw, const float* __restrict__ projb,
                      float* __restrict__ out) {
    __shared__ bf16_t aout[64*520];   // 66560 B
    __shared__ bf16_t P[64*72];       //  9216 B
    __shared__ bf16_t vT[32*72];      //  4608 B (stride 72: kills 16-way bank conflict)

    int b = blockIdx.x;
    int tid = threadIdx.x;
    int w = tid >> 6, lane = tid & 63, quad = lane >> 4, l16 = lane & 15;
    const bf16_t* base = qkv + (size_t)(b*64) * QKVN;
    f32x4 zero = {0.f, 0.f, 0.f, 0.f};
    int m0 = w * 16;

    // ---------------- phase 1: attention, head loop ----------------
    for (int h = 0; h < NHEADS; ++h) {
        // stage v transposed: vT[d][t], stride 72
        {
            int t = tid & 63, dg = tid >> 6;
            bf16x8 vv = *(const bf16x8*)(base + (size_t)t*QKVN + 1024 + h*32 + dg*8);
            for (int j = 0; j < 8; ++j) vT[(dg*8 + j)*72 + t] = vv[j];
        }

        // S = q k^T : A-frag = q rows, B-frag = k rows
        bf16x8 aq = *(const bf16x8*)(base + (size_t)(m0 + l16)*QKVN + h*32 + quad*8);
        f32x4 accS[4];
        for (int jt = 0; jt < 4; ++jt) {
            bf16x8 bk = *(const bf16x8*)(base + (size_t)(jt*16 + l16)*QKVN + 512 + h*32 + quad*8);
            accS[jt] = __builtin_amdgcn_mfma_f32_16x16x32_bf16(aq, bk, zero, 0, 0, 0);
        }

        // softmax in registers (row r = m0 + quad*4 + reg)
        const float* bh = bias + h*4096;
        float p[4][4], inv[4];
        for (int reg = 0; reg < 4; ++reg) {
            int row = m0 + quad*4 + reg;
            for (int jt = 0; jt < 4; ++jt)
                p[jt][reg] = accS[jt][reg] * SCALE + bh[row*64 + jt*16 + l16];
            float m = fmaxf(fmaxf(p[0][reg], p[1][reg]), fmaxf(p[2][reg], p[3][reg]));
            for (int off = 1; off < 16; off <<= 1) m = fmaxf(m, __shfl_xor(m, off));
            float s = 0.f;
            for (int jt = 0; jt < 4; ++jt) { p[jt][reg] = __expf(p[jt][reg] - m); s += p[jt][reg]; }
            for (int off = 1; off < 16; off <<= 1) s += __shfl_xor(s, off);
            inv[reg] = 1.0f / s;
        }
        for (int reg = 0; reg < 4; ++reg) {
            int row = m0 + quad*4 + reg;
            for (int jt = 0; jt < 4; ++jt)
                P[row*72 + jt*16 + l16] = (bf16_t)p[jt][reg];
        }
        __syncthreads();

        // O = P v : K=64 (2 steps), N=32 (2 tiles)
        f32x4 accO[2] = {zero, zero};
        for (int kb = 0; kb < 64; kb += 32) {
            bf16x8 ap = *(const bf16x8*)(&P[(m0 + l16)*72 + kb + quad*8]);
            for (int nt = 0; nt < 2; ++nt) {
                bf16x8 bv = *(const bf16x8*)(&vT[(nt*16 + l16)*72 + kb + quad*8]);
                accO[nt] = __builtin_amdgcn_mfma_f32_16x16x32_bf16(ap, bv, accO[nt], 0, 0, 0);
            }
        }
        // attnout -> LDS (bf16), rescaled by 1/rowsum
        for (int nt = 0; nt < 2; ++nt)
            for (int reg = 0; reg < 4; ++reg)
                aout[(m0 + quad*4 + reg)*520 + h*32 + nt*16 + l16] =
                    (bf16_t)(accO[nt][reg] * inv[reg]);
        __syncthreads();   // protects P/vT overwrite next iter; last iter guards aout for proj
    }

    // ---------------- phase 2: proj GEMM out = aout @ projw^T + projb -------
    // wave w owns output cols w*128 .. w*128+127, split in 2 halves of 64.
    for (int half = 0; half < 2; ++half) {
        f32x4 acc[4][4] = {};   // [mtile][ni]
        for (int kk = 0; kk < 512; kk += 32) {
            bf16x8 af[4], bfr[4];
            for (int mi = 0; mi < 4; ++mi)
                af[mi] = *(const bf16x8*)(&aout[(mi*16 + l16)*520 + kk + quad*8]);
            for (int ni = 0; ni < 4; ++ni)
                bfr[ni] = *(const bf16x8*)(projw + (size_t)(w*128 + half*64 + ni*16 + l16)*512 + kk + quad*8);
            for (int mi = 0; mi < 4; ++mi)
                for (int ni = 0; ni < 4; ++ni)
                    acc[mi][ni] = __builtin_amdgcn_mfma_f32_16x16x32_bf16(
                        af[mi], bfr[ni], acc[mi][ni], 0, 0, 0);
        }
        for (int ni = 0; ni < 4; ++ni) {
            int col = w*128 + half*64 + ni*16 + l16;
            float bv = projb[col];
            for (int mi = 0; mi < 4; ++mi) {
                int row0 = b*64 + mi*16 + quad*4;
                f32x4 a = acc[mi][ni];
                for (int reg = 0; reg < 4; ++reg)
                    out[(size_t)(row0 + reg)*DIM + col] = a[reg] + bv;
            }
        }
    }
}

// ---------------------------------------------------------------------------
extern "C" void kernel_launch(void* const* d_in, const int* in_sizes, int n_in,
                              void* d_out, int out_size, void* d_ws, size_t ws_size,
                              hipStream_t stream) {
    const float* x      = (const float*)d_in[0];
    const float* theta  = (const float*)d_in[1];
    const float* qkv_w  = (const float*)d_in[2];
    const float* qkv_b  = (const float*)d_in[3];
    const float* proj_w = (const float*)d_in[4];
    const float* proj_b = (const float*)d_in[5];
    const float* a_p    = (const float*)d_in[6];
    const float* b_p    = (const float*)d_in[7];
    const float* a_r    = (const float*)d_in[8];
    const float* b_r    = (const float*)d_in[9];
    float* out = (float*)d_out;

    // workspace layout (all 256B aligned)
    char* ws = (char*)d_ws;
    bf16_t* qkvbuf = (bf16_t*)ws;                                  // 65536*1536 bf16 = 192MB
    bf16_t* xb     = (bf16_t*)(ws + 201326592);                    // 65536*512  bf16 = 64MB
    bf16_t* wqkv   = (bf16_t*)(ws + 201326592 + 67108864);         // 1536*512 bf16
    bf16_t* wproj  = (bf16_t*)(ws + 201326592 + 67108864 + 1572864);
    float*  biasbf = (float*) (ws + 201326592 + 67108864 + 1572864 + 524288);

    // 1) converts
    cvt_f32_bf16<<<(MTOT*DIM/8)/256, 256, 0, stream>>>(x, xb, MTOT*DIM/8);
    cvt_f32_bf16<<<(QKVN*DIM/8)/256, 256, 0, stream>>>(qkv_w, wqkv, QKVN*DIM/8);
    cvt_f32_bf16<<<(DIM*DIM/8)/256, 256, 0, stream>>>(proj_w, wproj, DIM*DIM/8);

    // 2) bias table
    bias_kernel<<<256, 256, 0, stream>>>(a_p, b_p, a_r, b_r, theta, biasbf);

    // 3) qkv GEMM: M=65536 N=1536 K=512 (bf16 out)
    gemm_bt<1><<<(MTOT/128)*(QKVN/128), 256, 0, stream>>>(xb, wqkv, qkv_b, qkvbuf,
                                                          MTOT, QKVN, DIM, QKVN/128);
    // 4) fused attention + proj (fp32 out)
    attn_proj_kernel<<<NWIN, 256, 0, stream>>>(qkvbuf, biasbf, wproj, proj_b, out);
}

// Round 3
// 517.101 us; speedup vs baseline: 1.0794x; 1.0340x over previous
//
#include <hip/hip_runtime.h>
#include <hip/hip_bf16.h>

// ---------------------------------------------------------------------------
// swin_transformer_angular_tan: qkv GEMM -> fused (windowed attention + proj).
// B=1024 windows x 64 tokens, DIM=512, 16 heads x 32.
// Round 3: barrier-free phase-1 attention. Each wave owns 4 whole heads:
//   S^T = K Q^T  (C-layout: row=j, col=i)  -> softmax reduces over quads
//   P^T -> per-wave 1KB LDS buffer in MFMA B-frag order (no barrier)
//   O^T = V^T P^T, V^T A-frags via strided global loads (no LDS)
//   aout stored in LDS directly in proj A-frag order (64KB, conflict-free)
// ONE __syncthreads total, then proj streams projw from L2.
// ---------------------------------------------------------------------------

typedef __bf16 bf16_t;
typedef bf16_t bf16x8 __attribute__((ext_vector_type(8)));
typedef float  f32x4  __attribute__((ext_vector_type(4)));

#define NWIN   1024
#define NTOK   64
#define DIM    512
#define NHEADS 16
#define HD     32
#define MTOT   (NWIN*NTOK)      // 65536
#define QKVN   (3*DIM)          // 1536
#define SCALE  0.17677669529663687f   // 1/sqrt(32)

// ---------------- async global->LDS (16B per lane, wave-uniform LDS base) ---
__device__ __forceinline__ void async_copy16(const void* g, void* lds_generic) {
    __builtin_amdgcn_global_load_lds(
        (__attribute__((address_space(1))) unsigned int*)(unsigned long long)g,
        (__attribute__((address_space(3))) unsigned int*)(unsigned int)(unsigned long long)lds_generic,
        16, 0, 0);
}

// ---------------- fp32 -> bf16 convert (8 elems/thread) ---------------------
__global__ void cvt_f32_bf16(const float* __restrict__ in, bf16_t* __restrict__ out, int n8) {
    int i = blockIdx.x * blockDim.x + threadIdx.x;
    if (i >= n8) return;
    const float4* p = (const float4*)in;
    float4 a = p[2*i], b = p[2*i+1];
    bf16x8 o;
    o[0]=(bf16_t)a.x; o[1]=(bf16_t)a.y; o[2]=(bf16_t)a.z; o[3]=(bf16_t)a.w;
    o[4]=(bf16_t)b.x; o[5]=(bf16_t)b.y; o[6]=(bf16_t)b.z; o[7]=(bf16_t)b.w;
    ((bf16x8*)out)[i] = o;
}

// ---------------- bias table: bias[h][i][j], 16 x 64 x 64 -------------------
__global__ void bias_kernel(const float* __restrict__ ap, const float* __restrict__ bp,
                            const float* __restrict__ ar, const float* __restrict__ br,
                            const float* __restrict__ theta_max, float* __restrict__ bias) {
    int idx = blockIdx.x * 256 + threadIdx.x;   // 0..65535
    int h  = idx >> 12;
    int ij = idx & 4095;
    int i = ij >> 6, j = ij & 63;
    int ri = i >> 3, ci = i & 7, rj = j >> 3, cj = j & 7;
    int rad = ri - rj, az = ci - cj;              // -7..7
    int idx_r  = rad < 0 ? rad + 15 : rad;        // python % 15
    int idx_az = az  < 0 ? az  + 15 : az;
    float azang = (float)az * 0.19634954084936207f;       // 2*pi/32
    float rang  = (float)rad * (theta_max[0] * (1.0f/32.0f));
    float v = ap[idx_az*NHEADS + h] * cosf(azang) + bp[idx_az*NHEADS + h] * sinf(azang)
            + ar[idx_r *NHEADS + h] * cosf(rang)  + br[idx_r *NHEADS + h] * sinf(rang);
    bias[idx] = v;
}

// ---------------- BT-GEMM: C[M,N] = A[M,K] * Bt[N,K]^T + bias[N] ------------
// 128x128 tile, BK=64, 4 waves each 64x64 (4x4 MFMA 16x16x32).
// LDS tiles XOR-swizzled: row r, 16B-chunk cb stored at position cb^(r&7).
template<int OUT_BF16>
__global__ __launch_bounds__(256, 2)
void gemm_bt(const bf16_t* __restrict__ A, const bf16_t* __restrict__ Bt,
             const float* __restrict__ bias, void* __restrict__ C,
             int M, int N, int K, int ntiles) {
    __shared__ bf16_t sA[128*64];
    __shared__ bf16_t sB[128*64];

    int bid = blockIdx.x;
    int bm = bid / ntiles, bn = bid % ntiles;
    int tid = threadIdx.x;
    int w = tid >> 6, lane = tid & 63;
    int quad = lane >> 4, l16 = lane & 15;
    int wm = w >> 1, wn = w & 1;               // 2x2 wave grid

    f32x4 acc[4][4] = {};

    const bf16_t* Abase = A  + (size_t)(bm*128) * K;
    const bf16_t* Bbase = Bt + (size_t)(bn*128) * K;

    for (int k0 = 0; k0 < K; k0 += 64) {
        for (int i = 0; i < 4; ++i) {
            int off = w*4096 + i*1024 + lane*16;  // byte offset in tile
            int r  = off >> 7;                    // row (128B rows)
            int pb = (off >> 4) & 7;              // physical 16B chunk
            int cb = pb ^ (r & 7);                // logical chunk (swizzle)
            async_copy16(Abase + (size_t)r*K + k0 + cb*8, (char*)sA + w*4096 + i*1024);
            async_copy16(Bbase + (size_t)r*K + k0 + cb*8, (char*)sB + w*4096 + i*1024);
        }
        __syncthreads();

        for (int kk = 0; kk < 64; kk += 32) {
            bf16x8 af[4], bf[4];
            for (int mi = 0; mi < 4; ++mi) {
                int r  = wm*64 + mi*16 + l16;
                int cb = (kk >> 3) + quad;
                int pb = cb ^ (r & 7);
                af[mi] = *(const bf16x8*)((const char*)sA + r*128 + pb*16);
            }
            for (int ni = 0; ni < 4; ++ni) {
                int r  = wn*64 + ni*16 + l16;
                int cb = (kk >> 3) + quad;
                int pb = cb ^ (r & 7);
                bf[ni] = *(const bf16x8*)((const char*)sB + r*128 + pb*16);
            }
            for (int mi = 0; mi < 4; ++mi)
                for (int ni = 0; ni < 4; ++ni)
                    acc[mi][ni] = __builtin_amdgcn_mfma_f32_16x16x32_bf16(
                        af[mi], bf[ni], acc[mi][ni], 0, 0, 0);
        }
        __syncthreads();
    }

    for (int ni = 0; ni < 4; ++ni) {
        int col = bn*128 + wn*64 + ni*16 + l16;
        float bv = bias[col];
        for (int mi = 0; mi < 4; ++mi) {
            int row0 = bm*128 + wm*64 + mi*16 + quad*4;
            f32x4 a = acc[mi][ni];
            for (int reg = 0; reg < 4; ++reg) {
                float v = a[reg] + bv;
                size_t o = (size_t)(row0 + reg) * N + col;
                if (OUT_BF16) ((bf16_t*)C)[o] = (bf16_t)v;
                else          ((float*)C)[o]  = v;
            }
        }
    }
}

// ---------------- fused attention + proj: one block per window --------------
__global__ __launch_bounds__(256, 2)
void attn_proj_kernel(const bf16_t* __restrict__ qkv, const float* __restrict__ bias,
                      const bf16_t* __restrict__ projw, const float* __restrict__ projb,
                      float* __restrict__ out) {
    // aout in proj-A-frag order: frag (mi, h) at (mi*16+h)*512, 512 bf16 = 1KB.
    // Lane L of frag holds A[m = L&15][k = (L>>4)*8 + e] (k = c - h*32).
    __shared__ bf16_t aout[32768];    // 64KB
    __shared__ bf16_t pbuf[4][512];   // per-wave P^T B-frag staging, 1KB each

    int b = blockIdx.x;
    int tid = threadIdx.x;
    int w = tid >> 6, lane = tid & 63, quad = lane >> 4, l16 = lane & 15;
    const bf16_t* base = qkv + (size_t)(b*64) * QKVN;
    f32x4 zero = {0.f, 0.f, 0.f, 0.f};

    // ---------------- phase 1: 4 heads per wave, no barriers ----------------
    #pragma unroll 1
    for (int t = 0; t < 4; ++t) {
        int h = w*4 + t;

        // K rows -> S^T A-frags; Q rows -> S^T B-frags (both coalesced b128)
        bf16x8 ak[4], bq[4];
        #pragma unroll
        for (int jt = 0; jt < 4; ++jt)
            ak[jt] = *(const bf16x8*)(base + (size_t)(jt*16 + l16)*QKVN + 512 + h*32 + quad*8);
        #pragma unroll
        for (int it = 0; it < 4; ++it)
            bq[it] = *(const bf16x8*)(base + (size_t)(it*16 + l16)*QKVN + h*32 + quad*8);

        // V^T A-frags via strided scalar loads: elem e -> v[ks*32+quad*8+e][h*32+dt*16+l16]
        bf16x8 av[2][2];
        #pragma unroll
        for (int dt = 0; dt < 2; ++dt)
            #pragma unroll
            for (int ks = 0; ks < 2; ++ks) {
                const bf16_t* vb = base + (size_t)(ks*32 + quad*8)*QKVN + 1024 + h*32 + dt*16 + l16;
                bf16x8 tmp;
                #pragma unroll
                for (int e = 0; e < 8; ++e) tmp[e] = vb[(size_t)e*QKVN];
                av[dt][ks] = tmp;
            }

        // S^T = K Q^T : C-frag (jt,it): row j = jt*16+quad*4+reg, col i = it*16+l16
        f32x4 st[4][4];
        #pragma unroll
        for (int jt = 0; jt < 4; ++jt)
            #pragma unroll
            for (int it = 0; it < 4; ++it)
                st[jt][it] = __builtin_amdgcn_mfma_f32_16x16x32_bf16(ak[jt], bq[it], zero, 0, 0, 0);

        // logits = S^T*SCALE + bias[h][i][j]  (float4 along j: reg -> j = jt*16+quad*4+reg)
        const float* bh = bias + h*4096;
        float p[4][4][4];   // [jt][it][reg]
        #pragma unroll
        for (int it = 0; it < 4; ++it)
            #pragma unroll
            for (int jt = 0; jt < 4; ++jt) {
                float4 b4 = *(const float4*)(bh + (it*16 + l16)*64 + jt*16 + quad*4);
                p[jt][it][0] = st[jt][it][0]*SCALE + b4.x;
                p[jt][it][1] = st[jt][it][1]*SCALE + b4.y;
                p[jt][it][2] = st[jt][it][2]*SCALE + b4.z;
                p[jt][it][3] = st[jt][it][3]*SCALE + b4.w;
            }

        // softmax over j (rows of S^T) per column i = it*16+l16:
        // 16 in-lane values (jt x reg) + quad reduction (shfl 16,32)
        float inv[4];
        #pragma unroll
        for (int it = 0; it < 4; ++it) {
            float m = p[0][it][0];
            #pragma unroll
            for (int jt = 0; jt < 4; ++jt)
                #pragma unroll
                for (int r = 0; r < 4; ++r) m = fmaxf(m, p[jt][it][r]);
            m = fmaxf(m, __shfl_xor(m, 16));
            m = fmaxf(m, __shfl_xor(m, 32));
            float s = 0.f;
            #pragma unroll
            for (int jt = 0; jt < 4; ++jt)
                #pragma unroll
                for (int r = 0; r < 4; ++r) {
                    p[jt][it][r] = __expf(p[jt][it][r] - m);
                    s += p[jt][it][r];
                }
            s += __shfl_xor(s, 16);
            s += __shfl_xor(s, 32);
            inv[it] = 1.0f / s;
        }

        // O^T = V^T P^T, P^T staged per (ks,it) through per-wave 1KB frag buffer
        f32x4 accO[2][4];   // [dt][it]
        #pragma unroll
        for (int ks = 0; ks < 2; ++ks)
            #pragma unroll
            for (int it = 0; it < 4; ++it) {
                #pragma unroll
                for (int jh = 0; jh < 2; ++jh) {
                    int jt = ks*2 + jh;
                    #pragma unroll
                    for (int r = 0; r < 4; ++r) {
                        int jloc = jh*16 + quad*4 + r;   // k within this 32-window
                        pbuf[w][((jloc >> 3)*16 + l16)*8 + (jloc & 7)] = (bf16_t)p[jt][it][r];
                    }
                }
                bf16x8 bp = ((const bf16x8*)pbuf[w])[lane];   // compiler orders via lgkmcnt
                if (ks == 0) {
                    accO[0][it] = __builtin_amdgcn_mfma_f32_16x16x32_bf16(av[0][0], bp, zero, 0, 0, 0);
                    accO[1][it] = __builtin_amdgcn_mfma_f32_16x16x32_bf16(av[1][0], bp, zero, 0, 0, 0);
                } else {
                    accO[0][it] = __builtin_amdgcn_mfma_f32_16x16x32_bf16(av[0][1], bp, accO[0][it], 0, 0, 0);
                    accO[1][it] = __builtin_amdgcn_mfma_f32_16x16x32_bf16(av[1][1], bp, accO[1][it], 0, 0, 0);
                }
            }

        // write O (rescaled) into aout proj-A-frag layout
        #pragma unroll
        for (int dt = 0; dt < 2; ++dt)
            #pragma unroll
            for (int it = 0; it < 4; ++it) {
                #pragma unroll
                for (int r = 0; r < 4; ++r) {
                    int d = dt*16 + quad*4 + r;          // 0..31 within head
                    aout[(it*16 + h)*512 + ((d >> 3)*16 + l16)*8 + (d & 7)] =
                        (bf16_t)(accO[dt][it][r] * inv[it]);
                }
            }
    }

    __syncthreads();   // the ONE barrier

    // ---------------- phase 2: proj. wave w owns cols w*128..w*128+127 ------
    #pragma unroll 1
    for (int half = 0; half < 2; ++half) {
        f32x4 acc[4][4] = {};
        #pragma unroll 1
        for (int hk = 0; hk < 16; ++hk) {     // K-step = one head's 32 dims
            bf16x8 af[4], bw[4];
            #pragma unroll
            for (int mi = 0; mi < 4; ++mi)
                af[mi] = ((const bf16x8*)(aout + (mi*16 + hk)*512))[lane];
            #pragma unroll
            for (int ni = 0; ni < 4; ++ni)
                bw[ni] = *(const bf16x8*)(projw + (size_t)(w*128 + half*64 + ni*16 + l16)*512 + hk*32 + quad*8);
            #pragma unroll
            for (int mi = 0; mi < 4; ++mi)
                #pragma unroll
                for (int ni = 0; ni < 4; ++ni)
                    acc[mi][ni] = __builtin_amdgcn_mfma_f32_16x16x32_bf16(af[mi], bw[ni], acc[mi][ni], 0, 0, 0);
        }
        #pragma unroll
        for (int ni = 0; ni < 4; ++ni) {
            int col = w*128 + half*64 + ni*16 + l16;
            float bv = projb[col];
            #pragma unroll
            for (int mi = 0; mi < 4; ++mi) {
                int row0 = b*64 + mi*16 + quad*4;
                f32x4 a = acc[mi][ni];
                #pragma unroll
                for (int reg = 0; reg < 4; ++reg)
                    out[(size_t)(row0 + reg)*DIM + col] = a[reg] + bv;
            }
        }
    }
}

// ---------------------------------------------------------------------------
extern "C" void kernel_launch(void* const* d_in, const int* in_sizes, int n_in,
                              void* d_out, int out_size, void* d_ws, size_t ws_size,
                              hipStream_t stream) {
    const float* x      = (const float*)d_in[0];
    const float* theta  = (const float*)d_in[1];
    const float* qkv_w  = (const float*)d_in[2];
    const float* qkv_b  = (const float*)d_in[3];
    const float* proj_w = (const float*)d_in[4];
    const float* proj_b = (const float*)d_in[5];
    const float* a_p    = (const float*)d_in[6];
    const float* b_p    = (const float*)d_in[7];
    const float* a_r    = (const float*)d_in[8];
    const float* b_r    = (const float*)d_in[9];
    float* out = (float*)d_out;

    // workspace layout (all 256B aligned)
    char* ws = (char*)d_ws;
    bf16_t* qkvbuf = (bf16_t*)ws;                                  // 65536*1536 bf16 = 192MB
    bf16_t* xb     = (bf16_t*)(ws + 201326592);                    // 65536*512  bf16 = 64MB
    bf16_t* wqkv   = (bf16_t*)(ws + 201326592 + 67108864);         // 1536*512 bf16
    bf16_t* wproj  = (bf16_t*)(ws + 201326592 + 67108864 + 1572864);
    float*  biasbf = (float*) (ws + 201326592 + 67108864 + 1572864 + 524288);

    // 1) converts
    cvt_f32_bf16<<<(MTOT*DIM/8)/256, 256, 0, stream>>>(x, xb, MTOT*DIM/8);
    cvt_f32_bf16<<<(QKVN*DIM/8)/256, 256, 0, stream>>>(qkv_w, wqkv, QKVN*DIM/8);
    cvt_f32_bf16<<<(DIM*DIM/8)/256, 256, 0, stream>>>(proj_w, wproj, DIM*DIM/8);

    // 2) bias table (layout [h][i][j] — consumed directly by attn)
    bias_kernel<<<256, 256, 0, stream>>>(a_p, b_p, a_r, b_r, theta, biasbf);

    // 3) qkv GEMM: M=65536 N=1536 K=512 (bf16 out)
    gemm_bt<1><<<(MTOT/128)*(QKVN/128), 256, 0, stream>>>(xb, wqkv, qkv_b, qkvbuf,
                                                          MTOT, QKVN, DIM, QKVN/128);
    // 4) fused attention + proj (fp32 out)
    attn_proj_kernel<<<NWIN, 256, 0, stream>>>(qkvbuf, biasbf, wproj, proj_b, out);
}